// Round 10
// baseline (130.051 us; speedup 1.0000x reference)
//
#include <hip/hip_runtime.h>

// Problem dims
#define B_    2
#define NCAM_ 6
#define J_    23
#define HM_   160
#define W_    640
#define H_    512
#define D_    50

static constexpr long long HF_SIZE = (long long)B_ * J_ * D_ * D_ * D_;        // 5,750,000
static constexpr long long HP_SIZE = (long long)B_ * NCAM_ * J_ * H_ * W_;     // 90,439,680
static constexpr int NBJ = B_ * J_;                                            // 46
static constexpr int CHUNKS = 32;
static constexpr int SP_BLOCKS = NBJ * CHUNKS;                                 // 1472
static constexpr int NPLANES = B_ * NCAM_ * J_;                                // 276
static constexpr int W4 = W_ / 4;                                              // 160 f4 per canvas row
static constexpr int HM4 = HM_ / 4;                                            // 40 f4 per crop row
static constexpr int PLANE_F4 = H_ * W4;                                       // 81,920
static constexpr int INT_F4 = HM_ * W4;                                        // 25,600 (crop band)
static constexpr int EXT_F4 = PLANE_F4 - INT_F4;                               // 56,320
static constexpr int EXTB_PER_PLANE = 16;                                      // 3,520 f4/block
static constexpr int EXT_BLOCKS = NPLANES * EXTB_PER_PLANE;                    // 4416
static constexpr int INT_ROWS = NPLANES * HM_;                                 // 44,160 crop rows
static constexpr int ROWS_PER_WAVE = 8;                                        // 8 | 160 -> wave-uniform plane
static constexpr int INT_BLOCKS = INT_ROWS / (4 * ROWS_PER_WAVE);              // 1380
static constexpr int MIX_BLOCKS = INT_BLOCKS + EXT_BLOCKS;                     // 5796
static constexpr int TOTAL_BLOCKS = SP_BLOCKS + MIX_BLOCKS;                    // 7268

// ---------------------------------------------------------------------------
// R10 = R7 memory ops (no nt), new grid order:
//   [0, SP_BLOCKS)  softplus+reduce (short blocks, finish early for finalize)
//   [SP_BLOCKS, +MIX_BLOCKS)  INT and EXT interleaved 1:3 so pure-store EXT
//   blocks are resident from t=0 and INT latency chains hide among them.
// Softplus uses __expf/__logf (abs err ~1e-6 << 0.3125 threshold).
// ---------------------------------------------------------------------------
__global__ void fused_all(const float4* __restrict__ vol4,
                          float4* __restrict__ out_hf4,
                          float* __restrict__ partials,
                          const float4* __restrict__ hm4,
                          const int* __restrict__ centerHM,
                          float4* __restrict__ out_pad4) {
    const int gid = blockIdx.x;

    if (gid < SP_BLOCKS) {
        // ---- softplus + reduction (pair-wise exact index math) ----
        const int sg = gid;
        const int NE4 = (D_ * D_ * D_) / 4;              // 31,250
        const int bj = sg / CHUNKS;
        const int chunk = sg % CHUNKS;
        const long long base4 = (long long)bj * NE4;

        float s = 0.f, sx = 0.f, sy = 0.f, sz = 0.f;
        for (int i = chunk * blockDim.x + threadIdx.x; i < NE4; i += CHUNKS * blockDim.x) {
            const float4 v = vol4[base4 + i];
            float4 sp;
            sp.x = fmaxf(v.x, 0.f) + __logf(1.f + __expf(-fabsf(v.x)));
            sp.y = fmaxf(v.y, 0.f) + __logf(1.f + __expf(-fabsf(v.y)));
            sp.z = fmaxf(v.z, 0.f) + __logf(1.f + __expf(-fabsf(v.z)));
            sp.w = fmaxf(v.w, 0.f) + __logf(1.f + __expf(-fabsf(v.w)));
            out_hf4[base4 + i] = sp;
            // e0 = 4i is even -> z0 even <= 48, pair (z0, z0+1) never wraps.
            const int e0 = i * 4;
            const int t0 = e0 / D_;       const int z0 = e0 - t0 * D_;
            const int x0i = t0 / D_;      const int y0i = t0 - x0i * D_;
            const int e2 = e0 + 2;
            const int t2 = e2 / D_;       const int z2 = e2 - t2 * D_;
            const int x2i = t2 / D_;      const int y2i = t2 - x2i * D_;
            const float p01 = sp.x + sp.y;
            const float p23 = sp.z + sp.w;
            s  += p01 + p23;
            sx += p01 * (float)x0i + p23 * (float)x2i;
            sy += p01 * (float)y0i + p23 * (float)y2i;
            sz += sp.x * (float)z0 + sp.y * (float)(z0 + 1)
                + sp.z * (float)z2 + sp.w * (float)(z2 + 1);
        }

        #pragma unroll
        for (int off = 32; off > 0; off >>= 1) {
            s  += __shfl_down(s,  off, 64);
            sx += __shfl_down(sx, off, 64);
            sy += __shfl_down(sy, off, 64);
            sz += __shfl_down(sz, off, 64);
        }
        __shared__ float sm[4][4];
        const int lane = threadIdx.x & 63;
        const int wid  = threadIdx.x >> 6;
        if (lane == 0) {
            sm[0][wid] = s; sm[1][wid] = sx; sm[2][wid] = sy; sm[3][wid] = sz;
        }
        __syncthreads();
        if (threadIdx.x == 0) {
            float a0 = 0.f, a1 = 0.f, a2 = 0.f, a3 = 0.f;
            #pragma unroll
            for (int w = 0; w < 4; ++w) {
                a0 += sm[0][w]; a1 += sm[1][w]; a2 += sm[2][w]; a3 += sm[3][w];
            }
            partials[sg * 4 + 0] = a0;
            partials[sg * 4 + 1] = a1;
            partials[sg * 4 + 2] = a2;
            partials[sg * 4 + 3] = a3;
        }
        return;
    }

    // ---- canvas blocks: INT/EXT interleaved 1:3 ----
    const int idx = gid - SP_BLOCKS;                     // [0, MIX_BLOCKS)
    const bool is_int = ((idx & 3) == 0) && ((idx >> 2) < INT_BLOCKS);

    if (is_int) {
        const int int_id = idx >> 2;
        const int wgl  = int_id * 4 + (threadIdx.x >> 6);
        const int lane = threadIdx.x & 63;
        const float4 z = make_float4(0.f, 0.f, 0.f, 0.f);

        const int row0  = wgl * ROWS_PER_WAVE;           // 8 rows, same plane
        const int plane = row0 / HM_;                    // wave-uniform
        const int dy0   = row0 - plane * HM_;
        const int bcam  = plane / J_;

        const int cx = centerHM[bcam * 2 + 0];
        const int cy = centerHM[bcam * 2 + 1];
        const int x0 = min(max(cx / 2 - HM_ / 2, 0), W_ - HM_);
        const int y0 = min(max(cy / 2 - HM_ / 2, 0), H_ - HM_);
        const int q  = x0 >> 2;
        const int r  = x0 & 3;
        const int nspan = r ? (HM4 + 1) : HM4;           // 41 or 40
        const int cnt   = W4 - nspan;                    // 119 or 120

        const float4* __restrict__ src4 =
            hm4 + (long long)plane * (HM_ * HM4) + dy0 * HM4;
        float4* __restrict__ outp =
            out_pad4 + (long long)plane * PLANE_F4 + (y0 + dy0) * W4;

        // issue all 8 row loads first (8 independent loads in flight)
        float4 s[ROWS_PER_WAVE];
        #pragma unroll
        for (int i = 0; i < ROWS_PER_WAVE; ++i) {
            s[i] = (lane < HM4) ? src4[i * HM4 + lane] : z;
        }

        #pragma unroll
        for (int i = 0; i < ROWS_PER_WAVE; ++i) {
            float px = __shfl_up(s[i].x, 1, 64);
            float py = __shfl_up(s[i].y, 1, 64);
            float pz = __shfl_up(s[i].z, 1, 64);
            float pw = __shfl_up(s[i].w, 1, 64);
            if (lane == 0) { px = py = pz = pw = 0.f; }
            float4 v;
            switch (r) {                                 // wave-uniform
                case 0:  v = s[i]; break;
                case 1:  v = make_float4(pw, s[i].x, s[i].y, s[i].z); break;
                case 2:  v = make_float4(pz, pw, s[i].x, s[i].y); break;
                default: v = make_float4(py, pz, pw, s[i].x); break;
            }
            float4* __restrict__ outrow = outp + i * W4;
            if (lane < nspan) outrow[q + lane] = v;      // aligned packed store
            // zero complement of this row (write-once)
            if (lane < cnt) outrow[lane < q ? lane : lane + nspan] = z;
            const int l2 = lane + 64;
            if (l2 < cnt) outrow[l2 < q ? l2 : l2 + nspan] = z;
        }
        return;
    }

    // ---- exterior zero rows: two contiguous spans, pure stores ----
    {
        // count of INT blocks at or before idx
        const int ints_before = min((idx >> 2) + ((idx & 3) ? 1 : 0), INT_BLOCKS);
        const int ext_id = idx - ints_before;            // [0, EXT_BLOCKS)
        const int plane = ext_id >> 4;                   // / EXTB_PER_PLANE
        const int sub   = ext_id & (EXTB_PER_PLANE - 1);
        const int bcam  = plane / J_;                    // uniform (scalar)

        const int cy = centerHM[bcam * 2 + 1];
        const int y0 = min(max(cy / 2 - HM_ / 2, 0), H_ - HM_);
        const int top = y0 * W4;                         // f4 before crop band

        float4* __restrict__ outp = out_pad4 + (long long)plane * PLANE_F4;
        const float4 z = make_float4(0.f, 0.f, 0.f, 0.f);
        const int e_end = (sub + 1) * (EXT_F4 / EXTB_PER_PLANE);
        #pragma unroll 4
        for (int e = sub * (EXT_F4 / EXTB_PER_PLANE) + threadIdx.x; e < e_end; e += 256) {
            const int dst = e < top ? e : e + INT_F4;    // skip the crop band
            outp[dst] = z;
        }
    }
}

// ---------------------------------------------------------------------------
// Tiny finalize (1 block)
// ---------------------------------------------------------------------------
__global__ void finalize_points(const float* __restrict__ partials,
                                const float* __restrict__ c3d,
                                float* __restrict__ out_p3d) {
    const int bj = threadIdx.x;
    if (bj < NBJ) {
        const int b = bj / J_;
        float a0 = 0.f, a1 = 0.f, a2 = 0.f, a3 = 0.f;
        for (int c = 0; c < CHUNKS; ++c) {
            const float* p = &partials[(bj * CHUNKS + c) * 4];
            a0 += p[0]; a1 += p[1]; a2 += p[2]; a3 += p[3];
        }
        const float inv = 1.0f / a0;
        out_p3d[bj * 3 + 0] = a1 * inv * 4.0f - 100.0f + c3d[b * 3 + 0];
        out_p3d[bj * 3 + 1] = a2 * inv * 4.0f - 100.0f + c3d[b * 3 + 1];
        out_p3d[bj * 3 + 2] = a3 * inv * 4.0f - 100.0f + c3d[b * 3 + 2];
    }
}

extern "C" void kernel_launch(void* const* d_in, const int* in_sizes, int n_in,
                              void* d_out, int out_size, void* d_ws, size_t ws_size,
                              hipStream_t stream) {
    const float* hm_batch  = (const float*)d_in[0];   // [B,NCAM,J,HM,HM]
    const float* vol       = (const float*)d_in[1];   // [B,J,D,D,D]
    const float* c3d       = (const float*)d_in[2];   // [B,1,3]
    const int*   centerHM  = (const int*)d_in[3];     // [B,NCAM,2]

    float* out     = (float*)d_out;
    float* out_hf  = out;                              // heatmap_final
    float* out_pad = out + HF_SIZE;                    // heatmaps_padded (16B-aligned)
    float* out_p3d = out + HF_SIZE + HP_SIZE;          // points3D

    float* partials = (float*)d_ws;                    // [SP_BLOCKS*4]

    fused_all<<<TOTAL_BLOCKS, 256, 0, stream>>>(
        (const float4*)vol, (float4*)out_hf, partials,
        (const float4*)hm_batch, centerHM, (float4*)out_pad);

    finalize_points<<<1, 64, 0, stream>>>(partials, c3d, out_p3d);
}

// Round 11
// 93.379 us; speedup vs baseline: 1.3927x; 1.3927x over previous
//
#include <hip/hip_runtime.h>

// Problem dims
#define B_    2
#define NCAM_ 6
#define J_    23
#define HM_   160
#define W_    640
#define H_    512
#define D_    50

static constexpr long long HF_SIZE = (long long)B_ * J_ * D_ * D_ * D_;        // 5,750,000
static constexpr long long HP_SIZE = (long long)B_ * NCAM_ * J_ * H_ * W_;     // 90,439,680
static constexpr int NBJ = B_ * J_;                                            // 46
static constexpr int CHUNKS = 32;
static constexpr int SP_BLOCKS = NBJ * CHUNKS;                                 // 1472
static constexpr int NPLANES = B_ * NCAM_ * J_;                                // 276
static constexpr int W4 = W_ / 4;                                              // 160 f4 per canvas row
static constexpr int HM4 = HM_ / 4;                                            // 40 f4 per crop row
static constexpr int PLANE_F4 = H_ * W4;                                       // 81,920
static constexpr int INT_F4 = HM_ * W4;                                        // 25,600 (crop band)
static constexpr int EXT_F4 = PLANE_F4 - INT_F4;                               // 56,320
static constexpr int EXTB_PER_PLANE = 16;                                      // 3,520 f4/block
static constexpr int EXT_BLOCKS = NPLANES * EXTB_PER_PLANE;                    // 4416
static constexpr int INT_ROWS = NPLANES * HM_;                                 // 44,160 crop rows
static constexpr int ROWS_PER_WAVE = 8;                                        // 8 | 160 -> wave-uniform plane
static constexpr int INT_BLOCKS = INT_ROWS / (4 * ROWS_PER_WAVE);              // 1380
static constexpr int TOTAL_BLOCKS = INT_BLOCKS + SP_BLOCKS + EXT_BLOCKS;       // 7268

// ---------------------------------------------------------------------------
// R11 = exact revert to R7 (best measured: 93.8 us).
// One fused kernel, three roles (write-once canvas, all stores 16B-aligned,
// all global loads fully packed):
//  [0, INT_BLOCKS)   crop-band rows. Each wave owns 8 rows of ONE plane
//                    (wave-uniform plane/x0/y0/q/r, hoisted). All 8 row
//                    loads issued back-to-back (MLP=8), then rotate via
//                    shfl_up by uniform r, aligned stores + zero complement.
//  [+, SP_BLOCKS)    softplus + 4-way reduction -> partials
//  [+, EXT_BLOCKS)   exterior rows: two contiguous spans of pure zero stores
// ---------------------------------------------------------------------------
__global__ void fused_all(const float4* __restrict__ vol4,
                          float4* __restrict__ out_hf4,
                          float* __restrict__ partials,
                          const float4* __restrict__ hm4,
                          const int* __restrict__ centerHM,
                          float4* __restrict__ out_pad4) {
    const int gid = blockIdx.x;

    if (gid < INT_BLOCKS) {
        const int wgl  = gid * 4 + (threadIdx.x >> 6);   // wave id, 5520 total
        const int lane = threadIdx.x & 63;
        const float4 z = make_float4(0.f, 0.f, 0.f, 0.f);

        const int row0  = wgl * ROWS_PER_WAVE;           // 8 rows, same plane
        const int plane = row0 / HM_;                    // wave-uniform
        const int dy0   = row0 - plane * HM_;
        const int bcam  = plane / J_;

        const int cx = centerHM[bcam * 2 + 0];
        const int cy = centerHM[bcam * 2 + 1];
        const int x0 = min(max(cx / 2 - HM_ / 2, 0), W_ - HM_);
        const int y0 = min(max(cy / 2 - HM_ / 2, 0), H_ - HM_);
        const int q  = x0 >> 2;
        const int r  = x0 & 3;
        const int nspan = r ? (HM4 + 1) : HM4;           // 41 or 40
        const int cnt   = W4 - nspan;                    // 119 or 120

        const float4* __restrict__ src4 =
            hm4 + (long long)plane * (HM_ * HM4) + dy0 * HM4;
        float4* __restrict__ outp =
            out_pad4 + (long long)plane * PLANE_F4 + (y0 + dy0) * W4;

        // issue all 8 row loads first (8 independent loads in flight)
        float4 s[ROWS_PER_WAVE];
        #pragma unroll
        for (int i = 0; i < ROWS_PER_WAVE; ++i) {
            s[i] = (lane < HM4) ? src4[i * HM4 + lane] : z;
        }

        #pragma unroll
        for (int i = 0; i < ROWS_PER_WAVE; ++i) {
            float px = __shfl_up(s[i].x, 1, 64);
            float py = __shfl_up(s[i].y, 1, 64);
            float pz = __shfl_up(s[i].z, 1, 64);
            float pw = __shfl_up(s[i].w, 1, 64);
            if (lane == 0) { px = py = pz = pw = 0.f; }
            float4 v;
            switch (r) {                                 // wave-uniform
                case 0:  v = s[i]; break;
                case 1:  v = make_float4(pw, s[i].x, s[i].y, s[i].z); break;
                case 2:  v = make_float4(pz, pw, s[i].x, s[i].y); break;
                default: v = make_float4(py, pz, pw, s[i].x); break;
            }
            float4* __restrict__ outrow = outp + i * W4;
            if (lane < nspan) outrow[q + lane] = v;      // aligned packed store
            // zero complement of this row (write-once)
            if (lane < cnt) outrow[lane < q ? lane : lane + nspan] = z;
            const int l2 = lane + 64;
            if (l2 < cnt) outrow[l2 < q ? l2 : l2 + nspan] = z;
        }
        return;
    }

    if (gid < INT_BLOCKS + SP_BLOCKS) {
        // ---- softplus + reduction (pair-wise exact index math) ----
        const int sg = gid - INT_BLOCKS;
        const int NE4 = (D_ * D_ * D_) / 4;              // 31,250
        const int bj = sg / CHUNKS;
        const int chunk = sg % CHUNKS;
        const long long base4 = (long long)bj * NE4;

        float s = 0.f, sx = 0.f, sy = 0.f, sz = 0.f;
        for (int i = chunk * blockDim.x + threadIdx.x; i < NE4; i += CHUNKS * blockDim.x) {
            const float4 v = vol4[base4 + i];
            float4 sp;
            sp.x = fmaxf(v.x, 0.f) + log1pf(__expf(-fabsf(v.x)));
            sp.y = fmaxf(v.y, 0.f) + log1pf(__expf(-fabsf(v.y)));
            sp.z = fmaxf(v.z, 0.f) + log1pf(__expf(-fabsf(v.z)));
            sp.w = fmaxf(v.w, 0.f) + log1pf(__expf(-fabsf(v.w)));
            out_hf4[base4 + i] = sp;
            // e0 = 4i is even -> z0 even <= 48, pair (z0, z0+1) never wraps.
            const int e0 = i * 4;
            const int t0 = e0 / D_;       const int z0 = e0 - t0 * D_;
            const int x0i = t0 / D_;      const int y0i = t0 - x0i * D_;
            const int e2 = e0 + 2;
            const int t2 = e2 / D_;       const int z2 = e2 - t2 * D_;
            const int x2i = t2 / D_;      const int y2i = t2 - x2i * D_;
            const float p01 = sp.x + sp.y;
            const float p23 = sp.z + sp.w;
            s  += p01 + p23;
            sx += p01 * (float)x0i + p23 * (float)x2i;
            sy += p01 * (float)y0i + p23 * (float)y2i;
            sz += sp.x * (float)z0 + sp.y * (float)(z0 + 1)
                + sp.z * (float)z2 + sp.w * (float)(z2 + 1);
        }

        #pragma unroll
        for (int off = 32; off > 0; off >>= 1) {
            s  += __shfl_down(s,  off, 64);
            sx += __shfl_down(sx, off, 64);
            sy += __shfl_down(sy, off, 64);
            sz += __shfl_down(sz, off, 64);
        }
        __shared__ float sm[4][4];
        const int lane = threadIdx.x & 63;
        const int wid  = threadIdx.x >> 6;
        if (lane == 0) {
            sm[0][wid] = s; sm[1][wid] = sx; sm[2][wid] = sy; sm[3][wid] = sz;
        }
        __syncthreads();
        if (threadIdx.x == 0) {
            float a0 = 0.f, a1 = 0.f, a2 = 0.f, a3 = 0.f;
            #pragma unroll
            for (int w = 0; w < 4; ++w) {
                a0 += sm[0][w]; a1 += sm[1][w]; a2 += sm[2][w]; a3 += sm[3][w];
            }
            partials[sg * 4 + 0] = a0;
            partials[sg * 4 + 1] = a1;
            partials[sg * 4 + 2] = a2;
            partials[sg * 4 + 3] = a3;
        }
        return;
    }

    // ---- exterior zero rows: two contiguous spans, pure stores ----
    {
        const int pb    = gid - INT_BLOCKS - SP_BLOCKS;
        const int plane = pb >> 4;                       // / EXTB_PER_PLANE
        const int sub   = pb & (EXTB_PER_PLANE - 1);
        const int bcam  = plane / J_;                    // uniform (scalar)

        const int cy = centerHM[bcam * 2 + 1];
        const int y0 = min(max(cy / 2 - HM_ / 2, 0), H_ - HM_);
        const int top = y0 * W4;                         // f4 before crop band

        float4* __restrict__ outp = out_pad4 + (long long)plane * PLANE_F4;
        const float4 z = make_float4(0.f, 0.f, 0.f, 0.f);
        const int e_end = (sub + 1) * (EXT_F4 / EXTB_PER_PLANE);
        for (int e = sub * (EXT_F4 / EXTB_PER_PLANE) + threadIdx.x; e < e_end; e += 256) {
            const int dst = e < top ? e : e + INT_F4;    // skip the crop band
            outp[dst] = z;
        }
    }
}

// ---------------------------------------------------------------------------
// Tiny finalize (1 block)
// ---------------------------------------------------------------------------
__global__ void finalize_points(const float* __restrict__ partials,
                                const float* __restrict__ c3d,
                                float* __restrict__ out_p3d) {
    const int bj = threadIdx.x;
    if (bj < NBJ) {
        const int b = bj / J_;
        float a0 = 0.f, a1 = 0.f, a2 = 0.f, a3 = 0.f;
        for (int c = 0; c < CHUNKS; ++c) {
            const float* p = &partials[(bj * CHUNKS + c) * 4];
            a0 += p[0]; a1 += p[1]; a2 += p[2]; a3 += p[3];
        }
        const float inv = 1.0f / a0;
        out_p3d[bj * 3 + 0] = a1 * inv * 4.0f - 100.0f + c3d[b * 3 + 0];
        out_p3d[bj * 3 + 1] = a2 * inv * 4.0f - 100.0f + c3d[b * 3 + 1];
        out_p3d[bj * 3 + 2] = a3 * inv * 4.0f - 100.0f + c3d[b * 3 + 2];
    }
}

extern "C" void kernel_launch(void* const* d_in, const int* in_sizes, int n_in,
                              void* d_out, int out_size, void* d_ws, size_t ws_size,
                              hipStream_t stream) {
    const float* hm_batch  = (const float*)d_in[0];   // [B,NCAM,J,HM,HM]
    const float* vol       = (const float*)d_in[1];   // [B,J,D,D,D]
    const float* c3d       = (const float*)d_in[2];   // [B,1,3]
    const int*   centerHM  = (const int*)d_in[3];     // [B,NCAM,2]

    float* out     = (float*)d_out;
    float* out_hf  = out;                              // heatmap_final
    float* out_pad = out + HF_SIZE;                    // heatmaps_padded (16B-aligned)
    float* out_p3d = out + HF_SIZE + HP_SIZE;          // points3D

    float* partials = (float*)d_ws;                    // [SP_BLOCKS*4]

    fused_all<<<TOTAL_BLOCKS, 256, 0, stream>>>(
        (const float4*)vol, (float4*)out_hf, partials,
        (const float4*)hm_batch, centerHM, (float4*)out_pad);

    finalize_points<<<1, 64, 0, stream>>>(partials, c3d, out_p3d);
}